// Round 1
// baseline (313.369 us; speedup 1.0000x reference)
//
#include <hip/hip_runtime.h>

// Problem constants (from reference)
#define B_  4
#define N_  1
#define D_  48
#define H_  32
#define W_  88
#define C_  64
#define NX_ 200
#define NY_ 200
#define NZ_ 1
#define NPRIME (B_ * N_ * D_ * H_ * W_)   // 540,672 points
#define NXY    (NX_ * NY_)                // 40,000 bev cells

// ---------------------------------------------------------------------------
// Pass 2: scatter-add. One 64-lane wave per point; lane index = channel.
// Voxel index + keep mask are wave-uniform; early-out skips the x read.
// Accumulation grid layout (B, NX, NY, C): the 64 atomics per point are a
// contiguous 256 B burst.
// ---------------------------------------------------------------------------
__global__ __launch_bounds__(256)
void scatter_bxyc(const float* __restrict__ x,
                  const float* __restrict__ geom,
                  const float* __restrict__ sem,
                  const float* __restrict__ dxp,
                  const float* __restrict__ bxp,
                  float* __restrict__ grid)   // (B, NX, NY, C)
{
    int gid = blockIdx.x * 256 + threadIdx.x;
    int p = gid >> 6;          // point index (wave-uniform)
    int c = gid & 63;          // channel (lane)
    if (p >= NPRIME) return;

    // p -> (b, d, h, w), N = 1
    int w = p % W_;
    int t = p / W_;
    int h = t % H_;
    t /= H_;                   // t = b*D + d
    int b = t / D_;

    // semantic_mask[b, 1, h, w] > 0.5  (wave-uniform)
    float sm = sem[(b * 2 + 1) * (H_ * W_) + h * W_ + w];
    if (!(sm > 0.5f)) return;

    // match reference f32 arithmetic exactly: (geom - (bx - dx/2)) / dx, trunc
    float gxf = (geom[(size_t)p * 3 + 0] - (bxp[0] - dxp[0] * 0.5f)) / dxp[0];
    float gyf = (geom[(size_t)p * 3 + 1] - (bxp[1] - dxp[1] * 0.5f)) / dxp[1];
    float gzf = (geom[(size_t)p * 3 + 2] - (bxp[2] - dxp[2] * 0.5f)) / dxp[2];
    int gx = (int)gxf, gy = (int)gyf, gz = (int)gzf;
    if (gx < 0 || gx >= NX_ || gy < 0 || gy >= NY_ ||
        gz < 0 || gz >= NZ_) return;

    float val = x[(size_t)p * C_ + c];
    atomicAdd(&grid[(((size_t)b * NX_ + gx) * NY_ + gy) * C_ + c], val);
}

// ---------------------------------------------------------------------------
// Fallback (ws too small): scatter directly into out (B, C, NX, NY).
// Uncoalesced 4 B atomics, stride NX*NY between lanes.
// ---------------------------------------------------------------------------
__global__ __launch_bounds__(256)
void scatter_direct(const float* __restrict__ x,
                    const float* __restrict__ geom,
                    const float* __restrict__ sem,
                    const float* __restrict__ dxp,
                    const float* __restrict__ bxp,
                    float* __restrict__ out)   // (B, C, NX, NY)
{
    int gid = blockIdx.x * 256 + threadIdx.x;
    int p = gid >> 6;
    int c = gid & 63;
    if (p >= NPRIME) return;

    int w = p % W_;
    int t = p / W_;
    int h = t % H_;
    t /= H_;
    int b = t / D_;

    float sm = sem[(b * 2 + 1) * (H_ * W_) + h * W_ + w];
    if (!(sm > 0.5f)) return;

    float gxf = (geom[(size_t)p * 3 + 0] - (bxp[0] - dxp[0] * 0.5f)) / dxp[0];
    float gyf = (geom[(size_t)p * 3 + 1] - (bxp[1] - dxp[1] * 0.5f)) / dxp[1];
    float gzf = (geom[(size_t)p * 3 + 2] - (bxp[2] - dxp[2] * 0.5f)) / dxp[2];
    int gx = (int)gxf, gy = (int)gyf, gz = (int)gzf;
    if (gx < 0 || gx >= NX_ || gy < 0 || gy >= NY_ ||
        gz < 0 || gz >= NZ_) return;

    float val = x[(size_t)p * C_ + c];
    atomicAdd(&out[(((size_t)b * C_ + c) * NX_ + gx) * NY_ + gy], val);
}

// ---------------------------------------------------------------------------
// Pass 3: transpose (B, XY, C) -> (B, C, XY), 64x64 LDS tiles.
// Both global sides move in 256 B contiguous segments per 16-lane group.
// ---------------------------------------------------------------------------
__global__ __launch_bounds__(256)
void transpose_xyc_cxy(const float* __restrict__ grid,  // (B, NXY, C)
                       float* __restrict__ out)         // (B, C, NXY)
{
    __shared__ float tile[64][65];   // +1 pad breaks bank conflicts
    int b   = blockIdx.y;
    int xy0 = blockIdx.x * 64;

    int t    = threadIdx.x;
    int colv = t & 15;               // float4 slot 0..15
    int row0 = t >> 4;               // 0..15

    const float* src = grid + ((size_t)b * NXY + xy0) * C_;
    for (int rr = 0; rr < 4; ++rr) {
        int row = row0 + rr * 16;    // xy within tile
        float4 v = ((const float4*)(src + (size_t)row * C_))[colv];
        tile[row][colv * 4 + 0] = v.x;
        tile[row][colv * 4 + 1] = v.y;
        tile[row][colv * 4 + 2] = v.z;
        tile[row][colv * 4 + 3] = v.w;
    }
    __syncthreads();

    float* dst = out + (size_t)b * C_ * NXY + xy0;
    for (int rr = 0; rr < 4; ++rr) {
        int c = row0 + rr * 16;      // channel row
        float4 v;
        v.x = tile[colv * 4 + 0][c];
        v.y = tile[colv * 4 + 1][c];
        v.z = tile[colv * 4 + 2][c];
        v.w = tile[colv * 4 + 3][c];
        ((float4*)(dst + (size_t)c * NXY))[colv] = v;
    }
}

// ---------------------------------------------------------------------------
extern "C" void kernel_launch(void* const* d_in, const int* in_sizes, int n_in,
                              void* d_out, int out_size, void* d_ws, size_t ws_size,
                              hipStream_t stream)
{
    const float* x    = (const float*)d_in[0];   // (B,N,D,H,W,C)
    const float* geom = (const float*)d_in[1];   // (B,N,D,H,W,3)
    const float* sem  = (const float*)d_in[2];   // (B*N,2,H,W)
    const float* dxp  = (const float*)d_in[3];   // (3,)
    const float* bxp  = (const float*)d_in[4];   // (3,)
    float* out = (float*)d_out;                  // (B, C, NX, NY)

    const size_t gridBytes = (size_t)B_ * NXY * C_ * sizeof(float);  // ~41 MB
    const int nThreads = NPRIME * 64;            // 34,603,008
    const int nBlocks  = (nThreads + 255) / 256; // 135,168

    if (ws_size >= gridBytes) {
        float* grid = (float*)d_ws;
        hipMemsetAsync(grid, 0, gridBytes, stream);
        scatter_bxyc<<<nBlocks, 256, 0, stream>>>(x, geom, sem, dxp, bxp, grid);
        dim3 tg(NXY / 64, B_);
        transpose_xyc_cxy<<<tg, 256, 0, stream>>>(grid, out);
    } else {
        hipMemsetAsync(out, 0, gridBytes, stream);
        scatter_direct<<<nBlocks, 256, 0, stream>>>(x, geom, sem, dxp, bxp, out);
    }
}

// Round 2
// 299.497 us; speedup vs baseline: 1.0463x; 1.0463x over previous
//
#include <hip/hip_runtime.h>

// Problem constants (from reference)
#define B_  4
#define N_  1
#define D_  48
#define H_  32
#define W_  88
#define C_  64
#define NX_ 200
#define NY_ 200
#define NZ_ 1
#define NPRIME (B_ * N_ * D_ * H_ * W_)   // 540,672 points
#define NXY    (NX_ * NY_)                // 40,000 bev cells
#define NVOX   (B_ * NXY)                 // 160,000 voxels

// ---------------------------------------------------------------------------
// Kernel 1: per-point voxel id + histogram. One thread per point.
// ---------------------------------------------------------------------------
__global__ __launch_bounds__(256)
void hist_kernel(const float* __restrict__ geom,
                 const float* __restrict__ sem,
                 const float* __restrict__ dxp,
                 const float* __restrict__ bxp,
                 int* __restrict__ voxid,
                 int* __restrict__ counts)
{
    int p = blockIdx.x * 256 + threadIdx.x;   // NPRIME = 2112*256 exactly
    // p -> (b, d, h, w), N = 1
    int w = p % W_;
    int t = p / W_;
    int h = t % H_;
    t /= H_;                   // t = b*D + d
    int b = t / D_;

    int v = -1;
    float sm = sem[(b * 2 + 1) * (H_ * W_) + h * W_ + w];
    if (sm > 0.5f) {
        // match reference f32 arithmetic: (geom - (bx - dx/2)) / dx, trunc to 0
        float gxf = (geom[(size_t)p * 3 + 0] - (bxp[0] - dxp[0] * 0.5f)) / dxp[0];
        float gyf = (geom[(size_t)p * 3 + 1] - (bxp[1] - dxp[1] * 0.5f)) / dxp[1];
        float gzf = (geom[(size_t)p * 3 + 2] - (bxp[2] - dxp[2] * 0.5f)) / dxp[2];
        int gx = (int)gxf, gy = (int)gyf, gz = (int)gzf;
        if (gx >= 0 && gx < NX_ && gy >= 0 && gy < NY_ &&
            gz >= 0 && gz < NZ_) {
            v = b * NXY + gx * NY_ + gy;   // NZ==1 so gz==0
            atomicAdd(&counts[v], 1);
        }
    }
    voxid[p] = v;
}

// ---------------------------------------------------------------------------
// Scan pass 1: per-block (256-wide) exclusive scan of counts -> base,
// block totals -> partials. 625 blocks (NVOX = 625*256 exactly).
// ---------------------------------------------------------------------------
__global__ __launch_bounds__(256)
void scan1_kernel(const int* __restrict__ counts,
                  int* __restrict__ base,
                  int* __restrict__ partials)
{
    __shared__ int s[256];
    int t = threadIdx.x;
    int i = blockIdx.x * 256 + t;
    int c = counts[i];
    s[t] = c;
    __syncthreads();
    for (int off = 1; off < 256; off <<= 1) {
        int add = (t >= off) ? s[t - off] : 0;
        __syncthreads();
        s[t] += add;
        __syncthreads();
    }
    base[i] = s[t] - c;                 // exclusive within block
    if (t == 255) partials[blockIdx.x] = s[255];
}

// ---------------------------------------------------------------------------
// Scan pass 2: inclusive scan of 625 partials in one block (in-place).
// Also writes base[NVOX] = grand total.
// ---------------------------------------------------------------------------
__global__ __launch_bounds__(1024)
void scan2_kernel(int* __restrict__ partials, int* __restrict__ base)
{
    __shared__ int s[1024];
    int t = threadIdx.x;
    s[t] = (t < 625) ? partials[t] : 0;
    __syncthreads();
    for (int off = 1; off < 1024; off <<= 1) {
        int add = (t >= off) ? s[t - off] : 0;
        __syncthreads();
        s[t] += add;
        __syncthreads();
    }
    if (t < 625) partials[t] = s[t];    // inclusive scan
    if (t == 624) base[NVOX] = s[624];  // grand total
}

// ---------------------------------------------------------------------------
// Scan pass 3: add block offsets; init cursor = base.
// ---------------------------------------------------------------------------
__global__ __launch_bounds__(256)
void scan3_kernel(int* __restrict__ base,
                  const int* __restrict__ partials,
                  int* __restrict__ cursor)
{
    int blk = blockIdx.x;
    int i = blk * 256 + threadIdx.x;
    int off = (blk > 0) ? partials[blk - 1] : 0;
    int bv = base[i] + off;
    base[i] = bv;
    cursor[i] = bv;
}

// ---------------------------------------------------------------------------
// Kernel 5: fill per-voxel point lists.
// ---------------------------------------------------------------------------
__global__ __launch_bounds__(256)
void fill_kernel(const int* __restrict__ voxid,
                 int* __restrict__ cursor,
                 int* __restrict__ plist)
{
    int p = blockIdx.x * 256 + threadIdx.x;
    int v = voxid[p];
    if (v >= 0) {
        int slot = atomicAdd(&cursor[v], 1);
        plist[slot] = p;
    }
}

// ---------------------------------------------------------------------------
// Kernel 6: gather + fused transpose. Block = 256 thr (4 waves) handles 64
// consecutive voxels of one batch. Wave handles 16 voxels, lane = channel;
// register accumulation over the voxel's point list (coalesced 256 B reads
// of x per point). LDS 64x64 tile, then coalesced (B,C,X,Y) store.
// ---------------------------------------------------------------------------
__global__ __launch_bounds__(256)
void gather_kernel(const float* __restrict__ x,
                   const int* __restrict__ base,
                   const int* __restrict__ plist,
                   float* __restrict__ out)
{
    __shared__ float tile[64][65];      // [vox][ch], +1 pad
    int blk = blockIdx.x;               // 0..2499
    int b   = blk / 625;
    int xy0 = (blk % 625) * 64;
    int t    = threadIdx.x;
    int wave = t >> 6;
    int lane = t & 63;                  // channel
    int vbase = b * NXY + xy0;

    for (int i = 0; i < 16; ++i) {
        int vloc = wave * 16 + i;
        int v = vbase + vloc;
        int j0 = base[v], j1 = base[v + 1];
        float acc = 0.f;
        for (int j = j0; j < j1; ++j) {
            int p = plist[j];
            acc += x[(size_t)p * C_ + lane];
        }
        tile[vloc][lane] = acc;
    }
    __syncthreads();

    int col = t & 63;                   // xy within tile
    int rg  = t >> 6;                   // 0..3
    for (int it = 0; it < 16; ++it) {
        int ch = it * 4 + rg;
        out[((size_t)b * C_ + ch) * NXY + xy0 + col] = tile[col][ch];
    }
}

// ---------------------------------------------------------------------------
// Fallback (ws tiny): direct strided atomics into out (B, C, NX, NY).
// ---------------------------------------------------------------------------
__global__ __launch_bounds__(256)
void scatter_direct(const float* __restrict__ x,
                    const float* __restrict__ geom,
                    const float* __restrict__ sem,
                    const float* __restrict__ dxp,
                    const float* __restrict__ bxp,
                    float* __restrict__ out)
{
    int gid = blockIdx.x * 256 + threadIdx.x;
    int p = gid >> 6;
    int c = gid & 63;
    if (p >= NPRIME) return;
    int w = p % W_;
    int t = p / W_;
    int h = t % H_;
    t /= H_;
    int b = t / D_;
    float sm = sem[(b * 2 + 1) * (H_ * W_) + h * W_ + w];
    if (!(sm > 0.5f)) return;
    float gxf = (geom[(size_t)p * 3 + 0] - (bxp[0] - dxp[0] * 0.5f)) / dxp[0];
    float gyf = (geom[(size_t)p * 3 + 1] - (bxp[1] - dxp[1] * 0.5f)) / dxp[1];
    float gzf = (geom[(size_t)p * 3 + 2] - (bxp[2] - dxp[2] * 0.5f)) / dxp[2];
    int gx = (int)gxf, gy = (int)gyf, gz = (int)gzf;
    if (gx < 0 || gx >= NX_ || gy < 0 || gy >= NY_ ||
        gz < 0 || gz >= NZ_) return;
    float val = x[(size_t)p * C_ + c];
    atomicAdd(&out[(((size_t)b * C_ + c) * NX_ + gx) * NY_ + gy], val);
}

// ---------------------------------------------------------------------------
extern "C" void kernel_launch(void* const* d_in, const int* in_sizes, int n_in,
                              void* d_out, int out_size, void* d_ws, size_t ws_size,
                              hipStream_t stream)
{
    const float* x    = (const float*)d_in[0];   // (B,N,D,H,W,C)
    const float* geom = (const float*)d_in[1];   // (B,N,D,H,W,3)
    const float* sem  = (const float*)d_in[2];   // (B*N,2,H,W)
    const float* dxp  = (const float*)d_in[3];   // (3,)
    const float* bxp  = (const float*)d_in[4];   // (3,)
    float* out = (float*)d_out;                  // (B, C, NX, NY)

    // ws layout (1 MiB-aligned regions; total need ~10.5 MiB)
    char* wsb = (char*)d_ws;
    const size_t MB = 1024 * 1024;
    int* counts   = (int*)(wsb + 0 * MB);   // NVOX ints        (640 KB)
    int* base     = (int*)(wsb + 1 * MB);   // NVOX+1 ints      (640 KB)
    int* cursor   = (int*)(wsb + 2 * MB);   // NVOX ints        (640 KB)
    int* partials = (int*)(wsb + 3 * MB);   // 625 ints
    int* voxid    = (int*)(wsb + 4 * MB);   // NPRIME ints      (2.1 MB)
    int* plist    = (int*)(wsb + 7 * MB);   // NPRIME ints      (2.1 MB)
    const size_t wsNeed = 10 * MB;

    if (ws_size >= wsNeed) {
        hipMemsetAsync(counts, 0, (size_t)NVOX * sizeof(int), stream);
        hist_kernel<<<NPRIME / 256, 256, 0, stream>>>(geom, sem, dxp, bxp,
                                                      voxid, counts);
        scan1_kernel<<<NVOX / 256, 256, 0, stream>>>(counts, base, partials);
        scan2_kernel<<<1, 1024, 0, stream>>>(partials, base);
        scan3_kernel<<<NVOX / 256, 256, 0, stream>>>(base, partials, cursor);
        fill_kernel<<<NPRIME / 256, 256, 0, stream>>>(voxid, cursor, plist);
        gather_kernel<<<NVOX / 64, 256, 0, stream>>>(x, base, plist, out);
    } else {
        hipMemsetAsync(out, 0, (size_t)B_ * C_ * NXY * sizeof(float), stream);
        int nBlocks = (NPRIME * 64 + 255) / 256;
        scatter_direct<<<nBlocks, 256, 0, stream>>>(x, geom, sem, dxp, bxp, out);
    }
}